// Round 9
// baseline (371.688 us; speedup 1.0000x reference)
//
#include <hip/hip_runtime.h>
#include <stdint.h>

typedef unsigned short u16;
typedef __bf16 bf16x8 __attribute__((ext_vector_type(8)));
typedef float f32x4 __attribute__((ext_vector_type(4)));
typedef u16 u16x4 __attribute__((ext_vector_type(4)));

#define MFMA16(a, b, c) __builtin_amdgcn_mfma_f32_16x16x32_bf16((a), (b), (c), 0, 0, 0)

__device__ __forceinline__ u16 f2bf(float f) {
  uint32_t u = __builtin_bit_cast(uint32_t, f);
  u += 0x7FFFu + ((u >> 16) & 1u);  // RNE
  return (u16)(u >> 16);
}
__device__ __forceinline__ bf16x8 cvt8(f32x4 lo, f32x4 hi) {
  union { u16 u[8]; bf16x8 v; } r;
#pragma unroll
  for (int j = 0; j < 4; j++) { r.u[j] = f2bf(lo[j]); r.u[4 + j] = f2bf(hi[j]); }
  return r.v;
}
// async global->LDS, 16B per lane. LDS dest = wave-uniform base + lane*16.
__device__ __forceinline__ void gld_lds16(const void* g, void* l) {
  __builtin_amdgcn_global_load_lds(
      (const __attribute__((address_space(1))) uint32_t*)g,
      (__attribute__((address_space(3))) uint32_t*)l, 16, 0, 0);
}

// ---------------------------------------------------------------------------
// Fused prep (R7, proven): weight-interp vectorized 8 samples/thread
// (bf16x8 stores, bit-identical math). Blocks [0,8192): 4 weight curves;
// blocks [8192,12288): x f32->bf16.
// ---------------------------------------------------------------------------
__global__ void prep_kernel(const float* __restrict__ x, const float* __restrict__ cpq,
                            const float* __restrict__ cpk, const float* __restrict__ cpv,
                            const float* __restrict__ cpo, u16* __restrict__ xb,
                            u16* __restrict__ Wqkv, u16* __restrict__ Wo,
                            int n, double factor) {
  int blk = blockIdx.x;
  if (blk < 8192) {
    int base = (blk * 256 + threadIdx.x) * 8;    // < 4*4194304; 8 stay in-curve
    int w = base >> 22;
    int i = base & 4194303;
    const float* cp = (w == 0) ? cpq : (w == 1) ? cpk : (w == 2) ? cpv : cpo;
    union { u16 u[8]; bf16x8 v; } r;
#pragma unroll
    for (int s = 0; s < 8; s++) {
      double u = (double)(i + s) * factor;       // f64: f32 too coarse here
      int i0 = (int)u;
      if (i0 > n - 2) i0 = n - 2;
      float fr = (float)(u - (double)i0);
      float f0 = cp[i0], f1 = cp[i0 + 1];
      r.u[s] = f2bf(f0 + fr * (f1 - f0));
    }
    if (w < 3) *(bf16x8*)(Wqkv + base) = r.v;
    else       *(bf16x8*)(Wo + i) = r.v;
  } else {
    size_t i = ((size_t)(blk - 8192) * 256 + threadIdx.x) * 8;
    const f32x4* p = (const f32x4*)(x + i);
    *(bf16x8*)(xb + i) = cvt8(p[0], p[1]);
  }
}

// ---------------------------------------------------------------------------
// C[M,N] = A[M,2048] @ B[N,2048]^T, bf16 in, f32 acc. 128x128 tile, BK=64.
// PROVEN R0 kernel (MfmaUtil ~44%, 0 conflicts). Pipelined retiles R2-R4 all
// regressed (occupancy > source pipelining, m114 mechanism). GEMM arc closed.
// MODE 0: scatter bf16 to Q[B,H,S,D] (pre-scaled), K[B,H,S,D], Vt[B,H,D,S]
// MODE 1: row-major f32 [M,2048]
// ---------------------------------------------------------------------------
template <int MODE>
__global__ __launch_bounds__(256, 2)
void gemm_bt(const u16* __restrict__ A, const u16* __restrict__ B,
             u16* __restrict__ oQ, u16* __restrict__ oK, u16* __restrict__ oV,
             float* __restrict__ oC) {
  constexpr int KD = 2048;
  __shared__ __align__(16) u16 As[128 * 64];
  __shared__ __align__(16) u16 Bs[128 * 64];
  const int tid = threadIdx.x;
  const int wave = tid >> 6, lane = tid & 63, quad = lane >> 4, l16 = lane & 15;
  const int wm = wave & 1, wn = wave >> 1;
  const int m0 = blockIdx.y * 128, n0 = blockIdx.x * 128;

  size_t aoff[4], boff[4];
  int lslot[4];
#pragma unroll
  for (int b = 0; b < 4; b++) {
    int s = wave * 256 + b * 64 + lane;  // chunk slot 0..1023 (16B chunks)
    int r = s >> 3, c = s & 7, gc = c ^ (r & 7);
    lslot[b] = s * 16;
    aoff[b] = (size_t)(m0 + r) * (KD * 2) + gc * 16;
    boff[b] = (size_t)(n0 + r) * (KD * 2) + gc * 16;
  }
  const char* Ab = (const char*)A;
  const char* Bb = (const char*)B;
  char* AsB = (char*)As;
  char* BsB = (char*)Bs;

  f32x4 acc[4][4];
  const f32x4 fz = {0.f, 0.f, 0.f, 0.f};
#pragma unroll
  for (int i = 0; i < 4; i++)
#pragma unroll
    for (int j = 0; j < 4; j++) acc[i][j] = fz;

  for (int kt = 0; kt < KD / 64; ++kt) {
    if (kt) __syncthreads();
#pragma unroll
    for (int b = 0; b < 4; b++) {
      gld_lds16(Ab + aoff[b], AsB + lslot[b]);
      gld_lds16(Bb + boff[b], BsB + lslot[b]);
      aoff[b] += 128;
      boff[b] += 128;
    }
    __syncthreads();
#pragma unroll
    for (int t = 0; t < 2; t++) {
      bf16x8 af[4], bfb[4];
#pragma unroll
      for (int i = 0; i < 4; i++) {
        int row = wm * 64 + i * 16 + l16;
        int ch = (t * 4 + quad) ^ (row & 7);
        af[i] = *(const bf16x8*)(AsB + row * 128 + ch * 16);
      }
#pragma unroll
      for (int j = 0; j < 4; j++) {
        int row = wn * 64 + j * 16 + l16;
        int ch = (t * 4 + quad) ^ (row & 7);
        bfb[j] = *(const bf16x8*)(BsB + row * 128 + ch * 16);
      }
#pragma unroll
      for (int i = 0; i < 4; i++)
#pragma unroll
        for (int j = 0; j < 4; j++) acc[i][j] = MFMA16(af[i], bfb[j], acc[i][j]);
    }
  }

  // epilogue: C frag layout col=lane&15 (n), row=quad*4+reg (m)
  if (MODE == 0) {
    const float qscale = 0.08838834764831845f;  // folded into Q
#pragma unroll
    for (int j = 0; j < 4; j++) {
      int nb = n0 + wn * 64 + j * 16;
      int sel = nb >> 11;                      // 0=Q 1=K 2=V
      int h = (nb >> 7) & 15;
      int d = (nb & 127) + l16;
#pragma unroll
      for (int i = 0; i < 4; i++) {
        int mrow = m0 + wm * 64 + i * 16 + quad * 4;
        int bq = mrow >> 11, srow = mrow & 2047;
        if (sel == 2) {
          u16x4 pk = {f2bf(acc[i][j][0]), f2bf(acc[i][j][1]),
                      f2bf(acc[i][j][2]), f2bf(acc[i][j][3])};
          *(u16x4*)&oV[(size_t)(((bq << 4) + h) * 128 + d) * 2048 + srow] = pk;
        } else if (sel == 0) {
          int base = ((bq << 4) + h) * 2048;
#pragma unroll
          for (int r = 0; r < 4; r++)
            oQ[(size_t)(base + srow + r) * 128 + d] = f2bf(acc[i][j][r] * qscale);
        } else {
          int base = ((bq << 4) + h) * 2048;
#pragma unroll
          for (int r = 0; r < 4; r++)
            oK[(size_t)(base + srow + r) * 128 + d] = f2bf(acc[i][j][r]);
        }
      }
    }
  } else {
#pragma unroll
    for (int j = 0; j < 4; j++) {
      int col = n0 + wn * 64 + j * 16 + l16;
#pragma unroll
      for (int i = 0; i < 4; i++) {
        int mrow = m0 + wm * 64 + i * 16 + quad * 4;
#pragma unroll
        for (int r = 0; r < 4; r++) oC[(size_t)(mrow + r) * 2048 + col] = acc[i][j][r];
      }
    }
  }
}

// ---------------------------------------------------------------------------
// Causal flash attention, Bc=64, max-free softmax, TRANSPOSED QK.
// R9: NO K/V LDS STAGING. After R7's XCD head-grouping, each XCD's K/V
// working set (4 heads x 1MB) is L2-RESIDENT -- staging L2-fit data through
// LDS is pure overhead (guide Common-mistake #7 / m169). K and V fragments
// are now read DIRECTLY from global (L2-hit) at the exact bytes the staged
// path consumed (involutions cancel, verified):
//   QK A-frag: Kb + (k0+rowk)*256 + (t*4+quad)*16   [16 rows x 64B lines]
//   PV B-frag: Vb + vrow*4096 + (k0+t*32+quad*8)*2  [16 rows x 64B lines]
// Consequences: ZERO barriers in the kernel (Ps is wave-private), no
// vmcnt(0) drains, LDS 51200 -> 18432 B, fewer addressing VGPRs.
// R7 block mapping kept: XCD x owns heads 4x..4x+3 entirely.
// ---------------------------------------------------------------------------
__global__ __launch_bounds__(256, 2)
void flash_attn(const u16* __restrict__ Q, const u16* __restrict__ Kg,
                const u16* __restrict__ Vt, u16* __restrict__ attn) {
  __shared__ __align__(16) u16 Ps[128 * 72];
  const int tid = threadIdx.x;
  const int wave = tid >> 6, lane = tid & 63, quad = lane >> 4, l16 = lane & 15;
  const int L = blockIdx.x;
  const int g = L >> 3;
  const int s4 = g >> 2;
  const int qt = (s4 < 8) ? s4 : 23 - s4;
  const int bh = (L & 7) * 4 + (g & 3);
  const int q0 = qt * 128;
  const u16* Qb = Q + (size_t)bh * 2048 * 128;
  const u16* Kb = Kg + (size_t)bh * 2048 * 128;
  const u16* Vb = Vt + (size_t)bh * 128 * 2048;

  // Q B-frags: B[n=lane&15][k=quad*8+j], 2 n-tiles x 4 k-steps (d-chunks)
  bf16x8 qf[2][4];
#pragma unroll
  for (int i = 0; i < 2; i++) {
    int row = q0 + wave * 32 + i * 16 + l16;
#pragma unroll
    for (int t = 0; t < 4; t++)
      qf[i][t] = *(const bf16x8*)(Qb + (size_t)row * 128 + t * 32 + quad * 8);
  }

  f32x4 o_acc[2][8];
  const f32x4 fz = {0.f, 0.f, 0.f, 0.f};
#pragma unroll
  for (int i = 0; i < 2; i++)
#pragma unroll
    for (int j = 0; j < 8; j++) o_acc[i][j] = fz;
  float l_i[2] = {0.f, 0.f};  // per-lane partial row-sum for q = l16 (per i)

  const char* KbB = (const char*)Kb;
  const char* VbB = (const char*)Vb;

  const int ktmax = 2 * qt + 1;

  for (int kt = 0; kt <= ktmax; ++kt) {
    const int k0 = kt * 64;

    // S^T = K Q^T : A-frag = K row (contig d) direct from L2; B-frag = Q regs
    f32x4 st[2][4];
#pragma unroll
    for (int i = 0; i < 2; i++)
#pragma unroll
      for (int j = 0; j < 4; j++) st[i][j] = fz;
#pragma unroll
    for (int j = 0; j < 4; j++) {
      const char* Krow = KbB + (size_t)(k0 + j * 16 + l16) * 256;
#pragma unroll
      for (int t = 0; t < 4; t++) {
        bf16x8 kfr = *(const bf16x8*)(Krow + (t * 4 + quad) * 16);
        st[0][j] = MFMA16(kfr, qf[0][t], st[0][j]);
        st[1][j] = MFMA16(kfr, qf[1][t], st[1][j]);
      }
    }

    // max-free softmax; element (k = k0+j*16+quad*4+r, q = q0+wave*32+i*16+l16)
    const bool do_mask = (kt >= 2 * qt);
#pragma unroll
    for (int i = 0; i < 2; i++) {
      const int qg = q0 + wave * 32 + i * 16 + l16;
      float lacc = 0.f;
#pragma unroll
      for (int j = 0; j < 4; j++) {
        float p[4];
#pragma unroll
        for (int r = 0; r < 4; r++) {
          float v = st[i][j][r];
          if (do_mask && (k0 + j * 16 + quad * 4 + r > qg)) v = -1e30f;
          p[r] = __expf(v);  // Q pre-scaled; exp(-1e30) flushes to 0
        }
        lacc += (p[0] + p[1]) + (p[2] + p[3]);
        u16x4 pk = {f2bf(p[0]), f2bf(p[1]), f2bf(p[2]), f2bf(p[3])};
        *(u16x4*)&Ps[(wave * 32 + i * 16 + l16) * 72 + j * 16 + quad * 4] = pk;
      }
      l_i[i] += lacc;
    }
    // no barrier anywhere: each wave reads only its own 32 P rows

    // O += P V : A-frag from Ps rows (contig k); B-frag = Vt row direct L2
#pragma unroll
    for (int t = 0; t < 2; t++) {
      bf16x8 af0 = *(const bf16x8*)((char*)Ps + (wave * 32 + l16) * 144 + (t * 32 + quad * 8) * 2);
      bf16x8 af1 = *(const bf16x8*)((char*)Ps + (wave * 32 + 16 + l16) * 144 + (t * 32 + quad * 8) * 2);
      const char* Vcol = VbB + (size_t)(k0 + t * 32 + quad * 8) * 2;
#pragma unroll
      for (int j = 0; j < 8; j++) {
        bf16x8 bfr = *(const bf16x8*)(Vcol + (size_t)(j * 16 + l16) * 4096);
        o_acc[0][j] = MFMA16(af0, bfr, o_acc[0][j]);
        o_acc[1][j] = MFMA16(af1, bfr, o_acc[1][j]);
      }
    }
  }

  // epilogue: reduce l over quads (lanes with same l16 hold disjoint k-sets),
  // redistribute to o_acc's row ownership (row = quad*4+r), write.
  const int bb = bh >> 4, h = bh & 15;
#pragma unroll
  for (int i = 0; i < 2; i++) {
    float rs = l_i[i];
    rs += __shfl_xor(rs, 16);
    rs += __shfl_xor(rs, 32);
    float inv = 1.f / rs;  // valid for q-row = i*16 + l16
#pragma unroll
    for (int r = 0; r < 4; r++) {
      float invr = __shfl(inv, (lane & 48) | (quad * 4 + r), 64);
      int srow = q0 + wave * 32 + i * 16 + quad * 4 + r;
      size_t base = ((size_t)(bb * 2048 + srow)) * 2048 + h * 128;
#pragma unroll
      for (int j = 0; j < 8; j++) attn[base + j * 16 + l16] = f2bf(o_acc[i][j][r] * invr);
    }
  }
}

// ---------------------------------------------------------------------------
extern "C" void kernel_launch(void* const* d_in, const int* in_sizes, int n_in,
                              void* d_out, int out_size, void* d_ws, size_t ws_size,
                              hipStream_t stream) {
  (void)n_in; (void)out_size; (void)ws_size;
  const float* x = (const float*)d_in[0];     // [2,2048,2048] f32
  const float* cpq = (const float*)d_in[1];
  const float* cpk = (const float*)d_in[2];
  const float* cpv = (const float*)d_in[3];
  const float* cpo = (const float*)d_in[4];
  // d_in[5] = attention_mask: causal, applied analytically -> unused
  float* out = (float*)d_out;
  const int ncp = in_sizes[1];                // 32539
  const double factor = (double)(ncp - 1) / 4194303.0;

  char* ws = (char*)d_ws;
  u16* Wqkv = (u16*)(ws);                  // 6144*2048 bf16 = 25165824 B
  u16* At   = (u16*)(ws);                  // [B,S,H*D] 16MB, reuses dead Wqkv
  u16* Wo = (u16*)(ws + 25165824);         // 2048*2048 bf16 =  8388608 B
  u16* Qp = (u16*)(ws + 33554432);         // [B,H,S,D] bf16 = 16777216 B
  u16* Kp = (u16*)(ws + 50331648);         // [B,H,S,D]
  u16* Vp = (u16*)(ws + 67108864);         // [B,H,D,S]      (ends 80 MB)
  u16* xb = (u16*)d_out;                   // [4096,2048] bf16, dead before final GEMM

  prep_kernel<<<dim3(12288), dim3(256), 0, stream>>>(x, cpq, cpk, cpv, cpo, xb, Wqkv, Wo, ncp, factor);
  gemm_bt<0><<<dim3(48, 32), dim3(256), 0, stream>>>(xb, Wqkv, Qp, Kp, Vp, nullptr);
  flash_attn<<<dim3(512), dim3(256), 0, stream>>>(Qp, Kp, Vp, At);
  gemm_bt<1><<<dim3(16, 32), dim3(256), 0, stream>>>(At, Wo, nullptr, nullptr, nullptr, out);
}

// Round 10
// 324.019 us; speedup vs baseline: 1.1471x; 1.1471x over previous
//
#include <hip/hip_runtime.h>
#include <stdint.h>

typedef unsigned short u16;
typedef __bf16 bf16x8 __attribute__((ext_vector_type(8)));
typedef float f32x4 __attribute__((ext_vector_type(4)));
typedef u16 u16x4 __attribute__((ext_vector_type(4)));

#define MFMA16(a, b, c) __builtin_amdgcn_mfma_f32_16x16x32_bf16((a), (b), (c), 0, 0, 0)

__device__ __forceinline__ u16 f2bf(float f) {
  uint32_t u = __builtin_bit_cast(uint32_t, f);
  u += 0x7FFFu + ((u >> 16) & 1u);  // RNE
  return (u16)(u >> 16);
}
__device__ __forceinline__ bf16x8 cvt8(f32x4 lo, f32x4 hi) {
  union { u16 u[8]; bf16x8 v; } r;
#pragma unroll
  for (int j = 0; j < 4; j++) { r.u[j] = f2bf(lo[j]); r.u[4 + j] = f2bf(hi[j]); }
  return r.v;
}
// async global->LDS, 16B per lane. LDS dest = wave-uniform base + lane*16.
__device__ __forceinline__ void gld_lds16(const void* g, void* l) {
  __builtin_amdgcn_global_load_lds(
      (const __attribute__((address_space(1))) uint32_t*)g,
      (__attribute__((address_space(3))) uint32_t*)l, 16, 0, 0);
}

// ---------------------------------------------------------------------------
// Fused prep (R7, proven): weight-interp vectorized 8 samples/thread
// (bf16x8 stores, bit-identical math). Blocks [0,8192): 4 weight curves;
// blocks [8192,12288): x f32->bf16.
// ---------------------------------------------------------------------------
__global__ void prep_kernel(const float* __restrict__ x, const float* __restrict__ cpq,
                            const float* __restrict__ cpk, const float* __restrict__ cpv,
                            const float* __restrict__ cpo, u16* __restrict__ xb,
                            u16* __restrict__ Wqkv, u16* __restrict__ Wo,
                            int n, double factor) {
  int blk = blockIdx.x;
  if (blk < 8192) {
    int base = (blk * 256 + threadIdx.x) * 8;    // < 4*4194304; 8 stay in-curve
    int w = base >> 22;
    int i = base & 4194303;
    const float* cp = (w == 0) ? cpq : (w == 1) ? cpk : (w == 2) ? cpv : cpo;
    union { u16 u[8]; bf16x8 v; } r;
#pragma unroll
    for (int s = 0; s < 8; s++) {
      double u = (double)(i + s) * factor;       // f64: f32 too coarse here
      int i0 = (int)u;
      if (i0 > n - 2) i0 = n - 2;
      float fr = (float)(u - (double)i0);
      float f0 = cp[i0], f1 = cp[i0 + 1];
      r.u[s] = f2bf(f0 + fr * (f1 - f0));
    }
    if (w < 3) *(bf16x8*)(Wqkv + base) = r.v;
    else       *(bf16x8*)(Wo + i) = r.v;
  } else {
    size_t i = ((size_t)(blk - 8192) * 256 + threadIdx.x) * 8;
    const f32x4* p = (const f32x4*)(x + i);
    *(bf16x8*)(xb + i) = cvt8(p[0], p[1]);
  }
}

// ---------------------------------------------------------------------------
// C[M,N] = A[M,2048] @ B[N,2048]^T, bf16 in, f32 acc. 128x128 tile, BK=64.
// PROVEN R0 kernel (MfmaUtil ~44%, 0 conflicts). Pipelined retiles R2-R4 all
// regressed (occupancy > source pipelining, m114 mechanism). GEMM arc closed.
// MODE 0: scatter bf16 to Q[B,H,S,D] (pre-scaled), K[B,H,S,D], Vt[B,H,D,S]
// MODE 1: row-major f32 [M,2048]
// ---------------------------------------------------------------------------
template <int MODE>
__global__ __launch_bounds__(256, 2)
void gemm_bt(const u16* __restrict__ A, const u16* __restrict__ B,
             u16* __restrict__ oQ, u16* __restrict__ oK, u16* __restrict__ oV,
             float* __restrict__ oC) {
  constexpr int KD = 2048;
  __shared__ __align__(16) u16 As[128 * 64];
  __shared__ __align__(16) u16 Bs[128 * 64];
  const int tid = threadIdx.x;
  const int wave = tid >> 6, lane = tid & 63, quad = lane >> 4, l16 = lane & 15;
  const int wm = wave & 1, wn = wave >> 1;
  const int m0 = blockIdx.y * 128, n0 = blockIdx.x * 128;

  size_t aoff[4], boff[4];
  int lslot[4];
#pragma unroll
  for (int b = 0; b < 4; b++) {
    int s = wave * 256 + b * 64 + lane;  // chunk slot 0..1023 (16B chunks)
    int r = s >> 3, c = s & 7, gc = c ^ (r & 7);
    lslot[b] = s * 16;
    aoff[b] = (size_t)(m0 + r) * (KD * 2) + gc * 16;
    boff[b] = (size_t)(n0 + r) * (KD * 2) + gc * 16;
  }
  const char* Ab = (const char*)A;
  const char* Bb = (const char*)B;
  char* AsB = (char*)As;
  char* BsB = (char*)Bs;

  f32x4 acc[4][4];
  const f32x4 fz = {0.f, 0.f, 0.f, 0.f};
#pragma unroll
  for (int i = 0; i < 4; i++)
#pragma unroll
    for (int j = 0; j < 4; j++) acc[i][j] = fz;

  for (int kt = 0; kt < KD / 64; ++kt) {
    if (kt) __syncthreads();
#pragma unroll
    for (int b = 0; b < 4; b++) {
      gld_lds16(Ab + aoff[b], AsB + lslot[b]);
      gld_lds16(Bb + boff[b], BsB + lslot[b]);
      aoff[b] += 128;
      boff[b] += 128;
    }
    __syncthreads();
#pragma unroll
    for (int t = 0; t < 2; t++) {
      bf16x8 af[4], bfb[4];
#pragma unroll
      for (int i = 0; i < 4; i++) {
        int row = wm * 64 + i * 16 + l16;
        int ch = (t * 4 + quad) ^ (row & 7);
        af[i] = *(const bf16x8*)(AsB + row * 128 + ch * 16);
      }
#pragma unroll
      for (int j = 0; j < 4; j++) {
        int row = wn * 64 + j * 16 + l16;
        int ch = (t * 4 + quad) ^ (row & 7);
        bfb[j] = *(const bf16x8*)(BsB + row * 128 + ch * 16);
      }
#pragma unroll
      for (int i = 0; i < 4; i++)
#pragma unroll
        for (int j = 0; j < 4; j++) acc[i][j] = MFMA16(af[i], bfb[j], acc[i][j]);
    }
  }

  // epilogue: C frag layout col=lane&15 (n), row=quad*4+reg (m)
  if (MODE == 0) {
    const float qscale = 0.08838834764831845f;  // folded into Q
#pragma unroll
    for (int j = 0; j < 4; j++) {
      int nb = n0 + wn * 64 + j * 16;
      int sel = nb >> 11;                      // 0=Q 1=K 2=V
      int h = (nb >> 7) & 15;
      int d = (nb & 127) + l16;
#pragma unroll
      for (int i = 0; i < 4; i++) {
        int mrow = m0 + wm * 64 + i * 16 + quad * 4;
        int bq = mrow >> 11, srow = mrow & 2047;
        if (sel == 2) {
          u16x4 pk = {f2bf(acc[i][j][0]), f2bf(acc[i][j][1]),
                      f2bf(acc[i][j][2]), f2bf(acc[i][j][3])};
          *(u16x4*)&oV[(size_t)(((bq << 4) + h) * 128 + d) * 2048 + srow] = pk;
        } else if (sel == 0) {
          int base = ((bq << 4) + h) * 2048;
#pragma unroll
          for (int r = 0; r < 4; r++)
            oQ[(size_t)(base + srow + r) * 128 + d] = f2bf(acc[i][j][r] * qscale);
        } else {
          int base = ((bq << 4) + h) * 2048;
#pragma unroll
          for (int r = 0; r < 4; r++)
            oK[(size_t)(base + srow + r) * 128 + d] = f2bf(acc[i][j][r]);
        }
      }
    }
  } else {
#pragma unroll
    for (int j = 0; j < 4; j++) {
      int col = n0 + wn * 64 + j * 16 + l16;
#pragma unroll
      for (int i = 0; i < 4; i++) {
        int mrow = m0 + wm * 64 + i * 16 + quad * 4;
#pragma unroll
        for (int r = 0; r < 4; r++) oC[(size_t)(mrow + r) * 2048 + col] = acc[i][j][r];
      }
    }
  }
}

// ---------------------------------------------------------------------------
// Causal flash attention, Bc=64, max-free softmax, TRANSPOSED QK.
// R10 = R8-proven staged body (K/V via global_load_lds, 3 blocks/CU; R9's
// no-staging variant exposed raw L2 latency on the MFMA path: MfmaUtil 10%,
// 138 us -> reverted. Restructuring arc closed.)
// R7 XCD head-grouping kept (VALIDATED by R9: attn FETCH 24.6 MB ~= the
// compulsory K/V+Q traffic, so each XCD's 4 heads are L2-resident):
//   x=L&7, g=L>>3, bh=x*4+(g&3), s=g>>2, qt = s<8 ? s : 23-s
// R10 GRAFT: Ps pad-72 -> zero-pad stride-128 + XOR chunk swizzle (formula
// pair correctness-verified in R6; R9 attributed 1.67e6 conflict-cycles/
// dispatch to the pad-72 Ps). LDS 51200 -> 49152 B, still 3 blocks/CU.
//   write chunk = (2j+(quad>>1)) ^ (l16&7), +8B for odd quad
//   read  chunk = (t*4+quad)    ^ (l16&7)
// ---------------------------------------------------------------------------
__global__ __launch_bounds__(256, 2)
void flash_attn(const u16* __restrict__ Q, const u16* __restrict__ Kg,
                const u16* __restrict__ Vt, u16* __restrict__ attn) {
  __shared__ __align__(16) u16 Ks[64 * 128];
  __shared__ __align__(16) u16 Vs[128 * 64];
  __shared__ __align__(16) u16 Ps[128 * 64];
  const int tid = threadIdx.x;
  const int wave = tid >> 6, lane = tid & 63, quad = lane >> 4, l16 = lane & 15;
  const int L = blockIdx.x;
  const int g = L >> 3;
  const int s4 = g >> 2;
  const int qt = (s4 < 8) ? s4 : 23 - s4;
  const int bh = (L & 7) * 4 + (g & 3);
  const int q0 = qt * 128;
  const u16* Qb = Q + (size_t)bh * 2048 * 128;
  const u16* Kb = Kg + (size_t)bh * 2048 * 128;
  const u16* Vb = Vt + (size_t)bh * 128 * 2048;

  // Q B-frags: B[n=lane&15][k=quad*8+j], 2 n-tiles x 4 k-steps (d-chunks)
  bf16x8 qf[2][4];
#pragma unroll
  for (int i = 0; i < 2; i++) {
    int row = q0 + wave * 32 + i * 16 + l16;
#pragma unroll
    for (int t = 0; t < 4; t++)
      qf[i][t] = *(const bf16x8*)(Qb + (size_t)row * 128 + t * 32 + quad * 8);
  }

  f32x4 o_acc[2][8];
  const f32x4 fz = {0.f, 0.f, 0.f, 0.f};
#pragma unroll
  for (int i = 0; i < 2; i++)
#pragma unroll
    for (int j = 0; j < 8; j++) o_acc[i][j] = fz;
  float l_i[2] = {0.f, 0.f};  // per-lane partial row-sum for q = l16 (per i)

  int koff[4], voff[4], lslot[4];
#pragma unroll
  for (int b = 0; b < 4; b++) {
    int s = wave * 256 + b * 64 + lane;  // 0..1023
    lslot[b] = s * 16;
    {  // K-tile: 64 rows x 16 chunks; swizzle low 3 chunk bits by row
      int r = s >> 4, c = s & 15;
      int gc = (c & 8) | ((c & 7) ^ (r & 7));
      koff[b] = r * 256 + gc * 16;
    }
    {  // Vt-tile: 128 rows x 8 chunks (global row stride 4096 B)
      int r = s >> 3, c = s & 7;
      int gc = c ^ (r & 7);
      voff[b] = r * 4096 + gc * 16;
    }
  }
  const char* KbB = (const char*)Kb;
  const char* VbB = (const char*)Vb;
  char* KsB = (char*)Ks;
  char* VsB = (char*)Vs;
  char* PsB = (char*)Ps;
  const int ps_swz = l16 & 7;  // == row&7 for every Ps row this lane touches

  const int ktmax = 2 * qt + 1;

  for (int kt = 0; kt <= ktmax; ++kt) {
    const int k0 = kt * 64;
    if (kt) __syncthreads();
#pragma unroll
    for (int b = 0; b < 4; b++) {
      gld_lds16(KbB + (size_t)k0 * 256 + koff[b], KsB + lslot[b]);
      gld_lds16(VbB + (size_t)k0 * 2 + voff[b], VsB + lslot[b]);
    }
    __syncthreads();

    // S^T = K Q^T : A-frag = K row (contig d), m = k-col; B-frag = Q (regs)
    f32x4 st[2][4];
#pragma unroll
    for (int i = 0; i < 2; i++)
#pragma unroll
      for (int j = 0; j < 4; j++) st[i][j] = fz;
#pragma unroll
    for (int j = 0; j < 4; j++) {
      int rowk = j * 16 + l16;
#pragma unroll
      for (int t = 0; t < 4; t++) {
        int cc = t * 4 + quad;
        int ch = (cc & 8) | ((cc & 7) ^ (rowk & 7));
        bf16x8 kfr = *(const bf16x8*)(KsB + rowk * 256 + ch * 16);
        st[0][j] = MFMA16(kfr, qf[0][t], st[0][j]);
        st[1][j] = MFMA16(kfr, qf[1][t], st[1][j]);
      }
    }

    // max-free softmax; element (k = k0+j*16+quad*4+r, q = q0+wave*32+i*16+l16)
    const bool do_mask = (kt >= 2 * qt);
#pragma unroll
    for (int i = 0; i < 2; i++) {
      const int qg = q0 + wave * 32 + i * 16 + l16;
      float lacc = 0.f;
#pragma unroll
      for (int j = 0; j < 4; j++) {
        float p[4];
#pragma unroll
        for (int r = 0; r < 4; r++) {
          float v = st[i][j][r];
          if (do_mask && (k0 + j * 16 + quad * 4 + r > qg)) v = -1e30f;
          p[r] = __expf(v);  // Q pre-scaled; exp(-1e30) flushes to 0
        }
        lacc += (p[0] + p[1]) + (p[2] + p[3]);
        u16x4 pk = {f2bf(p[0]), f2bf(p[1]), f2bf(p[2]), f2bf(p[3])};
        // swizzled zero-pad store: elems j*16+quad*4.. -> chunk 2j+(quad>>1)
        int prow = wave * 32 + i * 16 + l16;
        *(u16x4*)(PsB + prow * 128 + (((j * 2 + (quad >> 1)) ^ ps_swz) * 16) +
                  (quad & 1) * 8) = pk;
      }
      l_i[i] += lacc;
    }
    // no barrier: each wave reads only its own 32 P rows (in-order DS)

    // O += P V : A-frag from Ps rows (contig k), B-frag = Vt row, n = d-col
#pragma unroll
    for (int t = 0; t < 2; t++) {
      int rch = ((t * 4 + quad) ^ ps_swz) * 16;
      bf16x8 af0 = *(const bf16x8*)(PsB + (wave * 32 + l16) * 128 + rch);
      bf16x8 af1 = *(const bf16x8*)(PsB + (wave * 32 + 16 + l16) * 128 + rch);
#pragma unroll
      for (int j = 0; j < 8; j++) {
        int vrow = j * 16 + l16;
        int ch = (t * 4 + quad) ^ (vrow & 7);
        bf16x8 bfr = *(const bf16x8*)(VsB + vrow * 128 + ch * 16);
        o_acc[0][j] = MFMA16(af0, bfr, o_acc[0][j]);
        o_acc[1][j] = MFMA16(af1, bfr, o_acc[1][j]);
      }
    }
  }

  // epilogue: reduce l over quads (lanes with same l16 hold disjoint k-sets),
  // redistribute to o_acc's row ownership (row = quad*4+r), write.
  const int bb = bh >> 4, h = bh & 15;
#pragma unroll
  for (int i = 0; i < 2; i++) {
    float rs = l_i[i];
    rs += __shfl_xor(rs, 16);
    rs += __shfl_xor(rs, 32);
    float inv = 1.f / rs;  // valid for q-row = i*16 + l16
#pragma unroll
    for (int r = 0; r < 4; r++) {
      float invr = __shfl(inv, (lane & 48) | (quad * 4 + r), 64);
      int srow = q0 + wave * 32 + i * 16 + quad * 4 + r;
      size_t base = ((size_t)(bb * 2048 + srow)) * 2048 + h * 128;
#pragma unroll
      for (int j = 0; j < 8; j++) attn[base + j * 16 + l16] = f2bf(o_acc[i][j][r] * invr);
    }
  }
}

// ---------------------------------------------------------------------------
extern "C" void kernel_launch(void* const* d_in, const int* in_sizes, int n_in,
                              void* d_out, int out_size, void* d_ws, size_t ws_size,
                              hipStream_t stream) {
  (void)n_in; (void)out_size; (void)ws_size;
  const float* x = (const float*)d_in[0];     // [2,2048,2048] f32
  const float* cpq = (const float*)d_in[1];
  const float* cpk = (const float*)d_in[2];
  const float* cpv = (const float*)d_in[3];
  const float* cpo = (const float*)d_in[4];
  // d_in[5] = attention_mask: causal, applied analytically -> unused
  float* out = (float*)d_out;
  const int ncp = in_sizes[1];                // 32539
  const double factor = (double)(ncp - 1) / 4194303.0;

  char* ws = (char*)d_ws;
  u16* Wqkv = (u16*)(ws);                  // 6144*2048 bf16 = 25165824 B
  u16* At   = (u16*)(ws);                  // [B,S,H*D] 16MB, reuses dead Wqkv
  u16* Wo = (u16*)(ws + 25165824);         // 2048*2048 bf16 =  8388608 B
  u16* Qp = (u16*)(ws + 33554432);         // [B,H,S,D] bf16 = 16777216 B
  u16* Kp = (u16*)(ws + 50331648);         // [B,H,S,D]
  u16* Vp = (u16*)(ws + 67108864);         // [B,H,D,S]      (ends 80 MB)
  u16* xb = (u16*)d_out;                   // [4096,2048] bf16, dead before final GEMM

  prep_kernel<<<dim3(12288), dim3(256), 0, stream>>>(x, cpq, cpk, cpv, cpo, xb, Wqkv, Wo, ncp, factor);
  gemm_bt<0><<<dim3(48, 32), dim3(256), 0, stream>>>(xb, Wqkv, Qp, Kp, Vp, nullptr);
  flash_attn<<<dim3(512), dim3(256), 0, stream>>>(Qp, Kp, Vp, At);
  gemm_bt<1><<<dim3(16, 32), dim3(256), 0, stream>>>(At, Wo, nullptr, nullptr, nullptr, out);
}

// Round 11
// 315.181 us; speedup vs baseline: 1.1793x; 1.0280x over previous
//
#include <hip/hip_runtime.h>
#include <stdint.h>

typedef unsigned short u16;
typedef __bf16 bf16x8 __attribute__((ext_vector_type(8)));
typedef float f32x4 __attribute__((ext_vector_type(4)));
typedef u16 u16x4 __attribute__((ext_vector_type(4)));

#define MFMA16(a, b, c) __builtin_amdgcn_mfma_f32_16x16x32_bf16((a), (b), (c), 0, 0, 0)

__device__ __forceinline__ u16 f2bf(float f) {
  uint32_t u = __builtin_bit_cast(uint32_t, f);
  u += 0x7FFFu + ((u >> 16) & 1u);  // RNE
  return (u16)(u >> 16);
}
__device__ __forceinline__ bf16x8 cvt8(f32x4 lo, f32x4 hi) {
  union { u16 u[8]; bf16x8 v; } r;
#pragma unroll
  for (int j = 0; j < 4; j++) { r.u[j] = f2bf(lo[j]); r.u[4 + j] = f2bf(hi[j]); }
  return r.v;
}
// async global->LDS, 16B per lane. LDS dest = wave-uniform base + lane*16.
__device__ __forceinline__ void gld_lds16(const void* g, void* l) {
  __builtin_amdgcn_global_load_lds(
      (const __attribute__((address_space(1))) uint32_t*)g,
      (__attribute__((address_space(3))) uint32_t*)l, 16, 0, 0);
}

// ---------------------------------------------------------------------------
// Fused prep (R7, proven): weight-interp vectorized 8 samples/thread
// (bf16x8 stores, bit-identical math). Blocks [0,8192): 4 weight curves;
// blocks [8192,12288): x f32->bf16.
// ---------------------------------------------------------------------------
__global__ void prep_kernel(const float* __restrict__ x, const float* __restrict__ cpq,
                            const float* __restrict__ cpk, const float* __restrict__ cpv,
                            const float* __restrict__ cpo, u16* __restrict__ xb,
                            u16* __restrict__ Wqkv, u16* __restrict__ Wo,
                            int n, double factor) {
  int blk = blockIdx.x;
  if (blk < 8192) {
    int base = (blk * 256 + threadIdx.x) * 8;    // < 4*4194304; 8 stay in-curve
    int w = base >> 22;
    int i = base & 4194303;
    const float* cp = (w == 0) ? cpq : (w == 1) ? cpk : (w == 2) ? cpv : cpo;
    union { u16 u[8]; bf16x8 v; } r;
#pragma unroll
    for (int s = 0; s < 8; s++) {
      double u = (double)(i + s) * factor;       // f64: f32 too coarse here
      int i0 = (int)u;
      if (i0 > n - 2) i0 = n - 2;
      float fr = (float)(u - (double)i0);
      float f0 = cp[i0], f1 = cp[i0 + 1];
      r.u[s] = f2bf(f0 + fr * (f1 - f0));
    }
    if (w < 3) *(bf16x8*)(Wqkv + base) = r.v;
    else       *(bf16x8*)(Wo + i) = r.v;
  } else {
    size_t i = ((size_t)(blk - 8192) * 256 + threadIdx.x) * 8;
    const f32x4* p = (const f32x4*)(x + i);
    *(bf16x8*)(xb + i) = cvt8(p[0], p[1]);
  }
}

// ---------------------------------------------------------------------------
// C[M,N] = A[M,2048] @ B[N,2048]^T, bf16 in, f32 acc. 128x128 tile, BK=64.
// PROVEN R0 body. R11: __launch_bounds__(256,2) -> (256,3).
// Rationale: cycle accounting shows neither MFMA (~310 cyc/tile-step) nor
// LDS (~750 cyc) saturated at the measured duration -> latency/issue-bound,
// and the cure is MORE co-resident blocks (m114 implicit overlap -- the
// mechanism that beat all 4 explicit pipelines this session). Resources fit
// a 3rd block: ~140 unified VGPR (76 arch + 64 acc) <= 170 (512/3 budget),
// 3 x 32KB LDS = 96KB <= 160KB. Grid 1536 at 3/CU = 2 EXACT rounds (vs 3).
// MODE 0: scatter bf16 to Q[B,H,S,D] (pre-scaled), K[B,H,S,D], Vt[B,H,D,S]
// MODE 1: row-major f32 [M,2048]
// ---------------------------------------------------------------------------
template <int MODE>
__global__ __launch_bounds__(256, 3)
void gemm_bt(const u16* __restrict__ A, const u16* __restrict__ B,
             u16* __restrict__ oQ, u16* __restrict__ oK, u16* __restrict__ oV,
             float* __restrict__ oC) {
  constexpr int KD = 2048;
  __shared__ __align__(16) u16 As[128 * 64];
  __shared__ __align__(16) u16 Bs[128 * 64];
  const int tid = threadIdx.x;
  const int wave = tid >> 6, lane = tid & 63, quad = lane >> 4, l16 = lane & 15;
  const int wm = wave & 1, wn = wave >> 1;
  const int m0 = blockIdx.y * 128, n0 = blockIdx.x * 128;

  size_t aoff[4], boff[4];
  int lslot[4];
#pragma unroll
  for (int b = 0; b < 4; b++) {
    int s = wave * 256 + b * 64 + lane;  // chunk slot 0..1023 (16B chunks)
    int r = s >> 3, c = s & 7, gc = c ^ (r & 7);
    lslot[b] = s * 16;
    aoff[b] = (size_t)(m0 + r) * (KD * 2) + gc * 16;
    boff[b] = (size_t)(n0 + r) * (KD * 2) + gc * 16;
  }
  const char* Ab = (const char*)A;
  const char* Bb = (const char*)B;
  char* AsB = (char*)As;
  char* BsB = (char*)Bs;

  f32x4 acc[4][4];
  const f32x4 fz = {0.f, 0.f, 0.f, 0.f};
#pragma unroll
  for (int i = 0; i < 4; i++)
#pragma unroll
    for (int j = 0; j < 4; j++) acc[i][j] = fz;

  for (int kt = 0; kt < KD / 64; ++kt) {
    if (kt) __syncthreads();
#pragma unroll
    for (int b = 0; b < 4; b++) {
      gld_lds16(Ab + aoff[b], AsB + lslot[b]);
      gld_lds16(Bb + boff[b], BsB + lslot[b]);
      aoff[b] += 128;
      boff[b] += 128;
    }
    __syncthreads();
#pragma unroll
    for (int t = 0; t < 2; t++) {
      bf16x8 af[4], bfb[4];
#pragma unroll
      for (int i = 0; i < 4; i++) {
        int row = wm * 64 + i * 16 + l16;
        int ch = (t * 4 + quad) ^ (row & 7);
        af[i] = *(const bf16x8*)(AsB + row * 128 + ch * 16);
      }
#pragma unroll
      for (int j = 0; j < 4; j++) {
        int row = wn * 64 + j * 16 + l16;
        int ch = (t * 4 + quad) ^ (row & 7);
        bfb[j] = *(const bf16x8*)(BsB + row * 128 + ch * 16);
      }
#pragma unroll
      for (int i = 0; i < 4; i++)
#pragma unroll
        for (int j = 0; j < 4; j++) acc[i][j] = MFMA16(af[i], bfb[j], acc[i][j]);
    }
  }

  // epilogue: C frag layout col=lane&15 (n), row=quad*4+reg (m)
  if (MODE == 0) {
    const float qscale = 0.08838834764831845f;  // folded into Q
#pragma unroll
    for (int j = 0; j < 4; j++) {
      int nb = n0 + wn * 64 + j * 16;
      int sel = nb >> 11;                      // 0=Q 1=K 2=V
      int h = (nb >> 7) & 15;
      int d = (nb & 127) + l16;
#pragma unroll
      for (int i = 0; i < 4; i++) {
        int mrow = m0 + wm * 64 + i * 16 + quad * 4;
        int bq = mrow >> 11, srow = mrow & 2047;
        if (sel == 2) {
          u16x4 pk = {f2bf(acc[i][j][0]), f2bf(acc[i][j][1]),
                      f2bf(acc[i][j][2]), f2bf(acc[i][j][3])};
          *(u16x4*)&oV[(size_t)(((bq << 4) + h) * 128 + d) * 2048 + srow] = pk;
        } else if (sel == 0) {
          int base = ((bq << 4) + h) * 2048;
#pragma unroll
          for (int r = 0; r < 4; r++)
            oQ[(size_t)(base + srow + r) * 128 + d] = f2bf(acc[i][j][r] * qscale);
        } else {
          int base = ((bq << 4) + h) * 2048;
#pragma unroll
          for (int r = 0; r < 4; r++)
            oK[(size_t)(base + srow + r) * 128 + d] = f2bf(acc[i][j][r]);
        }
      }
    }
  } else {
#pragma unroll
    for (int j = 0; j < 4; j++) {
      int col = n0 + wn * 64 + j * 16 + l16;
#pragma unroll
      for (int i = 0; i < 4; i++) {
        int mrow = m0 + wm * 64 + i * 16 + quad * 4;
#pragma unroll
        for (int r = 0; r < 4; r++) oC[(size_t)(mrow + r) * 2048 + col] = acc[i][j][r];
      }
    }
  }
}

// ---------------------------------------------------------------------------
// Causal flash attention, Bc=64, max-free softmax, TRANSPOSED QK.
// R10-proven body unchanged: staged K/V (R9 no-staging exposed L2 latency:
// 138us, reverted), R7 XCD head-grouping (validated: FETCH 24.6MB =
// compulsory), swizzled zero-pad Ps (conflicts 1.67e6 -> ~0). Keeps
// launch_bounds(256,2): ~184 unified VGPR (120+64 acc) > 170, so forcing a
// 3rd wave/SIMD would spill in the softmax loop.
// ---------------------------------------------------------------------------
__global__ __launch_bounds__(256, 2)
void flash_attn(const u16* __restrict__ Q, const u16* __restrict__ Kg,
                const u16* __restrict__ Vt, u16* __restrict__ attn) {
  __shared__ __align__(16) u16 Ks[64 * 128];
  __shared__ __align__(16) u16 Vs[128 * 64];
  __shared__ __align__(16) u16 Ps[128 * 64];
  const int tid = threadIdx.x;
  const int wave = tid >> 6, lane = tid & 63, quad = lane >> 4, l16 = lane & 15;
  const int L = blockIdx.x;
  const int g = L >> 3;
  const int s4 = g >> 2;
  const int qt = (s4 < 8) ? s4 : 23 - s4;
  const int bh = (L & 7) * 4 + (g & 3);
  const int q0 = qt * 128;
  const u16* Qb = Q + (size_t)bh * 2048 * 128;
  const u16* Kb = Kg + (size_t)bh * 2048 * 128;
  const u16* Vb = Vt + (size_t)bh * 128 * 2048;

  // Q B-frags: B[n=lane&15][k=quad*8+j], 2 n-tiles x 4 k-steps (d-chunks)
  bf16x8 qf[2][4];
#pragma unroll
  for (int i = 0; i < 2; i++) {
    int row = q0 + wave * 32 + i * 16 + l16;
#pragma unroll
    for (int t = 0; t < 4; t++)
      qf[i][t] = *(const bf16x8*)(Qb + (size_t)row * 128 + t * 32 + quad * 8);
  }

  f32x4 o_acc[2][8];
  const f32x4 fz = {0.f, 0.f, 0.f, 0.f};
#pragma unroll
  for (int i = 0; i < 2; i++)
#pragma unroll
    for (int j = 0; j < 8; j++) o_acc[i][j] = fz;
  float l_i[2] = {0.f, 0.f};  // per-lane partial row-sum for q = l16 (per i)

  int koff[4], voff[4], lslot[4];
#pragma unroll
  for (int b = 0; b < 4; b++) {
    int s = wave * 256 + b * 64 + lane;  // 0..1023
    lslot[b] = s * 16;
    {  // K-tile: 64 rows x 16 chunks; swizzle low 3 chunk bits by row
      int r = s >> 4, c = s & 15;
      int gc = (c & 8) | ((c & 7) ^ (r & 7));
      koff[b] = r * 256 + gc * 16;
    }
    {  // Vt-tile: 128 rows x 8 chunks (global row stride 4096 B)
      int r = s >> 3, c = s & 7;
      int gc = c ^ (r & 7);
      voff[b] = r * 4096 + gc * 16;
    }
  }
  const char* KbB = (const char*)Kb;
  const char* VbB = (const char*)Vb;
  char* KsB = (char*)Ks;
  char* VsB = (char*)Vs;
  char* PsB = (char*)Ps;
  const int ps_swz = l16 & 7;  // == row&7 for every Ps row this lane touches

  const int ktmax = 2 * qt + 1;

  for (int kt = 0; kt <= ktmax; ++kt) {
    const int k0 = kt * 64;
    if (kt) __syncthreads();
#pragma unroll
    for (int b = 0; b < 4; b++) {
      gld_lds16(KbB + (size_t)k0 * 256 + koff[b], KsB + lslot[b]);
      gld_lds16(VbB + (size_t)k0 * 2 + voff[b], VsB + lslot[b]);
    }
    __syncthreads();

    // S^T = K Q^T : A-frag = K row (contig d), m = k-col; B-frag = Q (regs)
    f32x4 st[2][4];
#pragma unroll
    for (int i = 0; i < 2; i++)
#pragma unroll
      for (int j = 0; j < 4; j++) st[i][j] = fz;
#pragma unroll
    for (int j = 0; j < 4; j++) {
      int rowk = j * 16 + l16;
#pragma unroll
      for (int t = 0; t < 4; t++) {
        int cc = t * 4 + quad;
        int ch = (cc & 8) | ((cc & 7) ^ (rowk & 7));
        bf16x8 kfr = *(const bf16x8*)(KsB + rowk * 256 + ch * 16);
        st[0][j] = MFMA16(kfr, qf[0][t], st[0][j]);
        st[1][j] = MFMA16(kfr, qf[1][t], st[1][j]);
      }
    }

    // max-free softmax; element (k = k0+j*16+quad*4+r, q = q0+wave*32+i*16+l16)
    const bool do_mask = (kt >= 2 * qt);
#pragma unroll
    for (int i = 0; i < 2; i++) {
      const int qg = q0 + wave * 32 + i * 16 + l16;
      float lacc = 0.f;
#pragma unroll
      for (int j = 0; j < 4; j++) {
        float p[4];
#pragma unroll
        for (int r = 0; r < 4; r++) {
          float v = st[i][j][r];
          if (do_mask && (k0 + j * 16 + quad * 4 + r > qg)) v = -1e30f;
          p[r] = __expf(v);  // Q pre-scaled; exp(-1e30) flushes to 0
        }
        lacc += (p[0] + p[1]) + (p[2] + p[3]);
        u16x4 pk = {f2bf(p[0]), f2bf(p[1]), f2bf(p[2]), f2bf(p[3])};
        // swizzled zero-pad store: elems j*16+quad*4.. -> chunk 2j+(quad>>1)
        int prow = wave * 32 + i * 16 + l16;
        *(u16x4*)(PsB + prow * 128 + (((j * 2 + (quad >> 1)) ^ ps_swz) * 16) +
                  (quad & 1) * 8) = pk;
      }
      l_i[i] += lacc;
    }
    // no barrier: each wave reads only its own 32 P rows (in-order DS)

    // O += P V : A-frag from Ps rows (contig k), B-frag = Vt row, n = d-col
#pragma unroll
    for (int t = 0; t < 2; t++) {
      int rch = ((t * 4 + quad) ^ ps_swz) * 16;
      bf16x8 af0 = *(const bf16x8*)(PsB + (wave * 32 + l16) * 128 + rch);
      bf16x8 af1 = *(const bf16x8*)(PsB + (wave * 32 + 16 + l16) * 128 + rch);
#pragma unroll
      for (int j = 0; j < 8; j++) {
        int vrow = j * 16 + l16;
        int ch = (t * 4 + quad) ^ (vrow & 7);
        bf16x8 bfr = *(const bf16x8*)(VsB + vrow * 128 + ch * 16);
        o_acc[0][j] = MFMA16(af0, bfr, o_acc[0][j]);
        o_acc[1][j] = MFMA16(af1, bfr, o_acc[1][j]);
      }
    }
  }

  // epilogue: reduce l over quads (lanes with same l16 hold disjoint k-sets),
  // redistribute to o_acc's row ownership (row = quad*4+r), write.
  const int bb = bh >> 4, h = bh & 15;
#pragma unroll
  for (int i = 0; i < 2; i++) {
    float rs = l_i[i];
    rs += __shfl_xor(rs, 16);
    rs += __shfl_xor(rs, 32);
    float inv = 1.f / rs;  // valid for q-row = i*16 + l16
#pragma unroll
    for (int r = 0; r < 4; r++) {
      float invr = __shfl(inv, (lane & 48) | (quad * 4 + r), 64);
      int srow = q0 + wave * 32 + i * 16 + quad * 4 + r;
      size_t base = ((size_t)(bb * 2048 + srow)) * 2048 + h * 128;
#pragma unroll
      for (int j = 0; j < 8; j++) attn[base + j * 16 + l16] = f2bf(o_acc[i][j][r] * invr);
    }
  }
}

// ---------------------------------------------------------------------------
extern "C" void kernel_launch(void* const* d_in, const int* in_sizes, int n_in,
                              void* d_out, int out_size, void* d_ws, size_t ws_size,
                              hipStream_t stream) {
  (void)n_in; (void)out_size; (void)ws_size;
  const float* x = (const float*)d_in[0];     // [2,2048,2048] f32
  const float* cpq = (const float*)d_in[1];
  const float* cpk = (const float*)d_in[2];
  const float* cpv = (const float*)d_in[3];
  const float* cpo = (const float*)d_in[4];
  // d_in[5] = attention_mask: causal, applied analytically -> unused
  float* out = (float*)d_out;
  const int ncp = in_sizes[1];                // 32539
  const double factor = (double)(ncp - 1) / 4194303.0;

  char* ws = (char*)d_ws;
  u16* Wqkv = (u16*)(ws);                  // 6144*2048 bf16 = 25165824 B
  u16* At   = (u16*)(ws);                  // [B,S,H*D] 16MB, reuses dead Wqkv
  u16* Wo = (u16*)(ws + 25165824);         // 2048*2048 bf16 =  8388608 B
  u16* Qp = (u16*)(ws + 33554432);         // [B,H,S,D] bf16 = 16777216 B
  u16* Kp = (u16*)(ws + 50331648);         // [B,H,S,D]
  u16* Vp = (u16*)(ws + 67108864);         // [B,H,D,S]      (ends 80 MB)
  u16* xb = (u16*)d_out;                   // [4096,2048] bf16, dead before final GEMM

  prep_kernel<<<dim3(12288), dim3(256), 0, stream>>>(x, cpq, cpk, cpv, cpo, xb, Wqkv, Wo, ncp, factor);
  gemm_bt<0><<<dim3(48, 32), dim3(256), 0, stream>>>(xb, Wqkv, Qp, Kp, Vp, nullptr);
  flash_attn<<<dim3(512), dim3(256), 0, stream>>>(Qp, Kp, Vp, At);
  gemm_bt<1><<<dim3(16, 32), dim3(256), 0, stream>>>(At, Wo, nullptr, nullptr, nullptr, out);
}